// Round 4
// baseline (197.747 us; speedup 1.0000x reference)
//
#include <hip/hip_runtime.h>
#include <hip/hip_bf16.h>

// ---------------------------------------------------------------------------
// ASL RNN.  Verified structure:
//  * recurrence never reads i2h -> only frame T-1 (512 samples) runs conv/fc.
//  * h_32 via 5 matrix squarings + vector recurrence (fp32 for accuracy).
// Round 4: 7 launches. Each launch = one squaring level (split-K=2, partials
// summed on load by the NEXT level -> no reduce kernels) co-scheduled with one
// feature-pipeline stage. mfma GEMM uses XCD-bound K-chunks (z = lid & 7).
// ---------------------------------------------------------------------------

typedef __attribute__((ext_vector_type(8))) unsigned short us8;
typedef __attribute__((ext_vector_type(8))) __bf16 bf8v;
typedef __attribute__((ext_vector_type(4))) float f4v;

static __device__ __forceinline__ unsigned short f2bf(float x) {
    __hip_bfloat16 h = __float2bfloat16(x);
    return *reinterpret_cast<unsigned short*>(&h);
}

static __device__ __forceinline__ void gload16(const void* g, void* s) {
    typedef __attribute__((address_space(1))) const void gv_t;
    typedef __attribute__((address_space(3))) void sv_t;
    __builtin_amdgcn_global_load_lds((gv_t*)g, (sv_t*)s, 16, 0, 0);
}

static __device__ __forceinline__ float4 ldg4_guard(
    const float* __restrict__ p, int r, int R, int c, int C, int ld)
{
    float4 v = make_float4(0.f, 0.f, 0.f, 0.f);
    if (r < R) {
        if (c + 3 < C) {
            v = *(const float4*)(p + (size_t)r * ld + c);
        } else {
            float tmp[4] = {0.f, 0.f, 0.f, 0.f};
            for (int u = 0; u < 4; ++u)
                if (c + u < C) tmp[u] = p[(size_t)r * ld + c + u];
            v = make_float4(tmp[0], tmp[1], tmp[2], tmp[3]);
        }
    }
    return v;
}

// sum-on-load of two split-K partials (p1 may be null -> single source)
static __device__ __forceinline__ float4 ldg4_guard2(
    const float* __restrict__ p0, const float* __restrict__ p1,
    int r, int R, int c, int C, int ld)
{
    float4 v = ldg4_guard(p0, r, R, c, C, ld);
    if (p1) {
        float4 w = ldg4_guard(p1, r, R, c, C, ld);
        v.x += w.x; v.y += w.y; v.z += w.z; v.w += w.w;
    }
    return v;
}

// ---------------------------------------------------------------------------
// device roles
// ---------------------------------------------------------------------------

// l2w (500x9504 f32) -> padded bf16 (512x9536)
static __device__ void dev_cvt(const float* __restrict__ W,
                               unsigned short* __restrict__ Wb,
                               int lid, int t)
{
    int idx = lid * 256 + t;
    int row = idx / 1192;
    int k8 = (idx - row * 1192) * 8;
    if (row >= 512) return;
    us8 o = (us8)0;
    if (row < 500 && k8 < 9504) {
        const float* p = W + (size_t)row * 9504 + k8;
        float4 v0 = *(const float4*)p;
        float4 v1 = *(const float4*)(p + 4);
        o[0] = f2bf(v0.x); o[1] = f2bf(v0.y); o[2] = f2bf(v0.z); o[3] = f2bf(v0.w);
        o[4] = f2bf(v1.x); o[5] = f2bf(v1.y); o[6] = f2bf(v1.z); o[7] = f2bf(v1.w);
    }
    *(us8*)(Wb + (size_t)row * 9536 + k8) = o;
}

// per-sample hand conv (2->16,k2)+relu+pool2, both hands
static __device__ void dev_hand(const float* __restrict__ hand,
    const float* __restrict__ lcw, const float* __restrict__ lcb,
    const float* __restrict__ rcw, const float* __restrict__ rcb,
    float* __restrict__ hpL, float* __restrict__ hpR,
    int b, int t, char* smem)
{
    float* x  = (float*)smem;        // 84
    float* cw = x + 84;              // 2*64
    float* cb = cw + 128;            // 2*16
    if (t < 84) x[t] = hand[(size_t)b * 84 + t];
    if (t < 64) { cw[t] = lcw[t]; cw[64 + t] = rcw[t]; }
    if (t < 16) { cb[t] = lcb[t]; cb[16 + t] = rcb[t]; }
    __syncthreads();
    for (int idx = t; idx < 608; idx += 256) {
        int hi = idx / 304, rem = idx % 304;
        int o = rem / 19, p = rem % 19;
        int off = hi * 42;
        const float* w = cw + hi * 64;
        float w00 = w[o*4], w01 = w[o*4+1], w10 = w[o*4+2], w11 = w[o*4+3];
        float bs = cb[hi * 16 + o];
        float c0 = w00*x[off+2*p]   + w01*x[off+2*p+2] +
                   w10*x[off+2*p+1] + w11*x[off+2*p+3] + bs;
        float c1 = w00*x[off+2*p+2] + w01*x[off+2*p+4] +
                   w10*x[off+2*p+3] + w11*x[off+2*p+5] + bs;
        float v = fmaxf(fmaxf(c0, c1), 0.f);
        (hi ? hpR : hpL)[(size_t)b * 304 + rem] = v;
    }
}

// squaring split-K=2 partial with sum-on-load sources:
// dst[z] = (s0+s1)[:, chunk_z] @ (s0+s1)[chunk_z, :]
static __device__ void dev_sq(const float* __restrict__ s0,
                              const float* __restrict__ s1,
                              float* __restrict__ dst,
                              int rid, int t, char* smem)
{
    float (*As)[68] = (float(*)[68])smem;
    float (*Bs)[68] = (float(*)[68])(smem + 4352);
    const int z = rid & 1;
    const int bm = ((rid >> 1) & 7) * 64, bn = ((rid >> 4) & 7) * 64;
    const int k0 = z * 250, kend = k0 + 250;
    const int lr = t >> 2, kq = (t & 3) * 4;
    const int kr = t >> 4, cq = (t & 15) * 4;
    const int ty = t >> 4, tx = t & 15;
    float acc[4][4] = {};
    float4 a0 = ldg4_guard2(s0, s1, bm + lr, 500, k0 + kq, kend, 500);
    float4 b0 = ldg4_guard2(s0, s1, k0 + kr, kend, bn + cq, 500, 500);
    for (int ks = 0; ks < 16; ++ks) {
        __syncthreads();
        As[kq+0][lr] = a0.x; As[kq+1][lr] = a0.y;
        As[kq+2][lr] = a0.z; As[kq+3][lr] = a0.w;
        *(float4*)&Bs[kr][cq] = b0;
        __syncthreads();
        if (ks < 15) {
            a0 = ldg4_guard2(s0, s1, bm + lr, 500, k0 + (ks+1)*16 + kq, kend, 500);
            b0 = ldg4_guard2(s0, s1, k0 + (ks+1)*16 + kr, kend, bn + cq, 500, 500);
        }
#pragma unroll
        for (int k = 0; k < 16; ++k) {
            float4 av = *(const float4*)&As[k][ty * 4];
            float4 bv = *(const float4*)&Bs[k][tx * 4];
            float aa[4] = {av.x, av.y, av.z, av.w};
            float bb[4] = {bv.x, bv.y, bv.z, bv.w};
#pragma unroll
            for (int i = 0; i < 4; ++i)
#pragma unroll
                for (int j = 0; j < 4; ++j)
                    acc[i][j] = fmaf(aa[i], bb[j], acc[i][j]);
        }
    }
    float* Cz = dst + (size_t)z * 250000;
#pragma unroll
    for (int i = 0; i < 4; ++i) {
        int m = bm + ty * 4 + i;
        if (m >= 500) continue;
#pragma unroll
        for (int j = 0; j < 4; ++j) {
            int n = bn + tx * 4 + j;
            if (n < 500) Cz[(size_t)m * 500 + n] = acc[i][j];
        }
    }
}

// un[j] = sum_a u[a]*(s0+s1)[j][a] + u[j]
static __device__ void dev_vec(const float* __restrict__ s0,
                               const float* __restrict__ s1,
                               const float* __restrict__ u,
                               float* __restrict__ un,
                               int j, int t, char* smem)
{
    float* red = (float*)smem;
    float s = 0.f;
    for (int a = t; a < 500; a += 256) {
        float p = s0[(size_t)j * 500 + a];
        if (s1) p += s1[(size_t)j * 500 + a];
        s += u[a] * p;
    }
    for (int off = 32; off; off >>= 1) s += __shfl_down(s, off);
    if ((t & 63) == 0) red[t >> 6] = s;
    __syncthreads();
    if (t == 0) un[j] = red[0] + red[1] + red[2] + red[3] + u[j];
}

// hand FC: both[m][hand*300+n] = relu(hp[m]@fw[n]^T + fb[n]),  K=304 exact
static __device__ void dev_fc(const float* __restrict__ hpL,
    const float* __restrict__ hpR, const float* __restrict__ lfw,
    const float* __restrict__ rfw, const float* __restrict__ lfb,
    const float* __restrict__ rfb, float* __restrict__ both,
    int rid, int t, char* smem)
{
    float (*As)[68] = (float(*)[68])smem;
    float (*Bs)[68] = (float(*)[68])(smem + 4352);
    const int hand = rid / 40, rem = rid % 40;
    const int bm = (rem / 5) * 64, bn = (rem % 5) * 64;
    const float* A = hand ? hpR : hpL;
    const float* B = hand ? rfw : lfw;
    const float* bias = hand ? rfb : lfb;
    const int lr = t >> 2, kq = (t & 3) * 4;
    const int ty = t >> 4, tx = t & 15;
    float acc[4][4] = {};
    float4 a0 = *(const float4*)(A + (size_t)(bm + lr) * 304 + kq);
    float4 b0 = (bn + lr < 300)
        ? *(const float4*)(B + (size_t)(bn + lr) * 304 + kq)
        : make_float4(0.f, 0.f, 0.f, 0.f);
    for (int ks = 0; ks < 19; ++ks) {
        __syncthreads();
        As[kq+0][lr] = a0.x; As[kq+1][lr] = a0.y;
        As[kq+2][lr] = a0.z; As[kq+3][lr] = a0.w;
        Bs[kq+0][lr] = b0.x; Bs[kq+1][lr] = b0.y;
        Bs[kq+2][lr] = b0.z; Bs[kq+3][lr] = b0.w;
        __syncthreads();
        if (ks < 18) {
            int kb = (ks + 1) * 16 + kq;
            a0 = *(const float4*)(A + (size_t)(bm + lr) * 304 + kb);
            b0 = (bn + lr < 300)
                ? *(const float4*)(B + (size_t)(bn + lr) * 304 + kb)
                : make_float4(0.f, 0.f, 0.f, 0.f);
        }
#pragma unroll
        for (int k = 0; k < 16; ++k) {
            float4 av = *(const float4*)&As[k][ty * 4];
            float4 bv = *(const float4*)&Bs[k][tx * 4];
            float aa[4] = {av.x, av.y, av.z, av.w};
            float bb[4] = {bv.x, bv.y, bv.z, bv.w};
#pragma unroll
            for (int i = 0; i < 4; ++i)
#pragma unroll
                for (int j = 0; j < 4; ++j)
                    acc[i][j] = fmaf(aa[i], bb[j], acc[i][j]);
        }
    }
#pragma unroll
    for (int i = 0; i < 4; ++i) {
        int m = bm + ty * 4 + i;
#pragma unroll
        for (int j = 0; j < 4; ++j) {
            int n = bn + tx * 4 + j;
            if (n < 300)
                both[(size_t)m * 600 + hand * 300 + n] =
                    fmaxf(acc[i][j] + bias[n], 0.f);
        }
    }
}

// conv2+relu+pool3 -> bf16 feat row (9536, tail zero)
static __device__ void dev_conv2(const float* __restrict__ both,
    const float* __restrict__ w2g, const float* __restrict__ b2g,
    unsigned short* __restrict__ feat, int b, int t, char* smem)
{
    float* s  = (float*)smem;       // 600
    float* w2 = s + 600;            // 128
    float* b2 = w2 + 128;           // 32
    for (int i = t; i < 600; i += 256) s[i] = both[(size_t)b * 600 + i];
    if (t < 128) w2[t] = w2g[t];
    if (t < 32) b2[t] = b2g[t];
    __syncthreads();
    for (int idx = t; idx < 9536; idx += 256) {
        unsigned short ov = 0;
        if (idx < 9504) {
            int o = idx / 297, p = idx - o * 297;
            float w0 = w2[o*4], w1 = w2[o*4+1], wv = w2[o*4+2], w3 = w2[o*4+3];
            float bb = b2[o];
            float m = -1e30f;
#pragma unroll
            for (int q = 0; q < 3; ++q) {
                float c = w0*s[p+q] + w1*s[p+q+1] + wv*s[300+p+q] + w3*s[301+p+q] + bb;
                m = fmaxf(m, c);
            }
            ov = f2bf(fmaxf(m, 0.f));
        }
        feat[(size_t)b * 9536 + idx] = ov;
    }
}

// bf16 MFMA split-K partials, 64x64 tile, XCD-bound: z = lid & 7
#define KSTR 9536
static __device__ void dev_mfma(const unsigned short* __restrict__ A,
    const unsigned short* __restrict__ B, float* __restrict__ Cp,
    int lid, int t, char* smem)
{
    unsigned short (*Al)[4096] = (unsigned short(*)[4096])smem;
    unsigned short (*Bl)[4096] = (unsigned short(*)[4096])(smem + 16384);
    const int z = lid & 7;
    const int bm = ((lid >> 3) & 7) * 64, bn = ((lid >> 6) & 7) * 64;
    int s0 = z * 19, s1 = s0 + 19; if (s1 > 149) s1 = 149;
    const int ns = s1 - s0;
    const int w = t >> 6, l = t & 63;
    const int srow = l >> 3;
    const int sslot = (l & 7) ^ srow;
    const int wm = (w >> 1) * 32, wn = (w & 1) * 32;
    const int fr = l & 15, jj = l >> 4;
    f4v acc[2][2] = {};

    const unsigned short* Ab = A + (size_t)(bm + 16*w + srow) * KSTR + sslot * 8;
    const unsigned short* Bb = B + (size_t)(bn + 16*w + srow) * KSTR + sslot * 8;

#define STAGE(buf, st)                                                          \
    {                                                                           \
        size_t k0 = (size_t)(s0 + (st)) * 64;                                   \
        _Pragma("unroll")                                                       \
        for (int q = 0; q < 2; ++q) {                                           \
            gload16(Ab + (size_t)(8*q) * KSTR + k0, &Al[buf][(16*w + 8*q)*64]); \
            gload16(Bb + (size_t)(8*q) * KSTR + k0, &Bl[buf][(16*w + 8*q)*64]); \
        }                                                                       \
    }
#define COMPUTE(buf)                                                            \
    {                                                                           \
        _Pragma("unroll")                                                       \
        for (int kk = 0; kk < 2; ++kk) {                                        \
            bf8v af[2], bf[2];                                                  \
            _Pragma("unroll")                                                   \
            for (int f = 0; f < 2; ++f) {                                       \
                int rA = wm + f * 16 + fr;                                      \
                int pA = (jj + 4*kk) ^ (rA & 7);                                \
                af[f] = __builtin_bit_cast(bf8v,                                \
                        *(const us8*)&Al[buf][rA * 64 + pA * 8]);               \
                int rB = wn + f * 16 + fr;                                      \
                int pB = (jj + 4*kk) ^ (rB & 7);                                \
                bf[f] = __builtin_bit_cast(bf8v,                                \
                        *(const us8*)&Bl[buf][rB * 64 + pB * 8]);               \
            }                                                                   \
            _Pragma("unroll")                                                   \
            for (int fi = 0; fi < 2; ++fi)                                      \
                _Pragma("unroll")                                               \
                for (int fj = 0; fj < 2; ++fj)                                  \
                    acc[fi][fj] = __builtin_amdgcn_mfma_f32_16x16x32_bf16(      \
                        af[fi], bf[fj], acc[fi][fj], 0, 0, 0);                  \
        }                                                                       \
    }

    STAGE(0, 0);
    __syncthreads();
    int cur = 0;
    for (int st = 0; st < ns; ++st) {
        if (st + 1 < ns) STAGE(cur ^ 1, st + 1);
        COMPUTE(cur);
        __syncthreads();
        cur ^= 1;
    }
    float* Cz = Cp + (size_t)z * 262144;
#pragma unroll
    for (int fi = 0; fi < 2; ++fi)
#pragma unroll
        for (int fj = 0; fj < 2; ++fj)
#pragma unroll
            for (int r = 0; r < 4; ++r) {
                int m = bm + wm + fi * 16 + jj * 4 + r;
                int n = bn + wn + fj * 16 + fr;
                Cz[(size_t)m * 512 + n] = acc[fi][fj][r];
            }
#undef STAGE
#undef COMPUTE
}

// h split-K=2 partial: Hsum[z] = hidden[:,chunk] @ (q0+q1)[:,chunk]^T
static __device__ void dev_hbt(const float* __restrict__ A,
    const float* __restrict__ q0, const float* __restrict__ q1,
    float* __restrict__ Hsum, int rid, int t, char* smem)
{
    float (*As)[68] = (float(*)[68])smem;
    float (*Bs)[68] = (float(*)[68])(smem + 4352);
    const int z = rid & 1;
    const int bm = ((rid >> 1) & 7) * 64, bn = ((rid >> 4) & 7) * 64;
    const int k0 = z * 250, kend = k0 + 250;
    const int lr = t >> 2, kq = (t & 3) * 4;
    const int ty = t >> 4, tx = t & 15;
    float acc[4][4] = {};
    float4 a0 = ldg4_guard(A, bm + lr, 512, k0 + kq, kend, 500);
    float4 b0 = ldg4_guard2(q0, q1, bn + lr, 500, k0 + kq, kend, 500);
    for (int ks = 0; ks < 16; ++ks) {
        __syncthreads();
        As[kq+0][lr] = a0.x; As[kq+1][lr] = a0.y;
        As[kq+2][lr] = a0.z; As[kq+3][lr] = a0.w;
        Bs[kq+0][lr] = b0.x; Bs[kq+1][lr] = b0.y;
        Bs[kq+2][lr] = b0.z; Bs[kq+3][lr] = b0.w;
        __syncthreads();
        if (ks < 15) {
            a0 = ldg4_guard(A, bm + lr, 512, k0 + (ks+1)*16 + kq, kend, 500);
            b0 = ldg4_guard2(q0, q1, bn + lr, 500, k0 + (ks+1)*16 + kq, kend, 500);
        }
#pragma unroll
        for (int k = 0; k < 16; ++k) {
            float4 av = *(const float4*)&As[k][ty * 4];
            float4 bv = *(const float4*)&Bs[k][tx * 4];
            float aa[4] = {av.x, av.y, av.z, av.w};
            float bb[4] = {bv.x, bv.y, bv.z, bv.w};
#pragma unroll
            for (int i = 0; i < 4; ++i)
#pragma unroll
                for (int j = 0; j < 4; ++j)
                    acc[i][j] = fmaf(aa[i], bb[j], acc[i][j]);
        }
    }
    float* Cz = Hsum + (size_t)z * 256000;
#pragma unroll
    for (int i = 0; i < 4; ++i) {
        int m = bm + ty * 4 + i;
#pragma unroll
        for (int j = 0; j < 4; ++j) {
            int n = bn + tx * 4 + j;
            if (n < 500) Cz[(size_t)m * 500 + n] = acc[i][j];
        }
    }
}

// ---------------------------------------------------------------------------
// merged launches
// ---------------------------------------------------------------------------
__global__ __launch_bounds__(256, 2) void prep0(
    const float* l2w, unsigned short* wbf,
    const float* hand31, const float* lcw, const float* lcb,
    const float* rcw, const float* rcb, float* hpL, float* hpR,
    const float* hw, float* Q, const float* hb, float* u1)
{
    __shared__ alignas(16) char smem[9216];
    const int lid = blockIdx.x, t = threadIdx.x;
    if (lid < 2384)       dev_cvt(l2w, wbf, lid, t);
    else if (lid < 2896)  dev_hand(hand31, lcw, lcb, rcw, rcb, hpL, hpR,
                                   lid - 2384, t, smem);
    else if (lid < 3024)  dev_sq(hw, nullptr, Q, lid - 2896, t, smem);
    else                  dev_vec(hw, nullptr, hb, u1, lid - 3024, t, smem);
}

__global__ __launch_bounds__(256, 2) void step1(
    const float* hpL, const float* hpR, const float* lfw, const float* rfw,
    const float* lfb, const float* rfb, float* both,
    const float* Q, float* R, const float* u1, float* u2)
{
    __shared__ alignas(16) char smem[9216];
    const int lid = blockIdx.x, t = threadIdx.x;
    if (lid < 80)         dev_fc(hpL, hpR, lfw, rfw, lfb, rfb, both, lid, t, smem);
    else if (lid < 208)   dev_sq(Q, Q + 250000, R, lid - 80, t, smem);
    else                  dev_vec(Q, Q + 250000, u1, u2, lid - 208, t, smem);
}

__global__ __launch_bounds__(256, 2) void step2(
    const float* both, const float* w2, const float* b2, unsigned short* featb,
    const float* R, float* Q, const float* u2, float* u3)
{
    __shared__ alignas(16) char smem[9216];
    const int lid = blockIdx.x, t = threadIdx.x;
    if (lid < 512)        dev_conv2(both, w2, b2, featb, lid, t, smem);
    else if (lid < 640)   dev_sq(R, R + 250000, Q, lid - 512, t, smem);
    else                  dev_vec(R, R + 250000, u2, u3, lid - 640, t, smem);
}

__global__ __launch_bounds__(256, 2) void step3(
    const unsigned short* featb, const unsigned short* wbf, float* Cp,
    const float* Q, float* R, const float* u3, float* u4)
{
    __shared__ alignas(16) char smem[32768];
    const int lid = blockIdx.x, t = threadIdx.x;
    if (lid < 512)        dev_mfma(featb, wbf, Cp, lid, t, smem);   // offset 0: z==XCD
    else if (lid < 640)   dev_sq(Q, Q + 250000, R, lid - 512, t, smem);
    else                  dev_vec(Q, Q + 250000, u3, u4, lid - 640, t, smem);
}

__global__ __launch_bounds__(256, 2) void step4(
    const float* R, float* Q, const float* u4, float* u5)
{
    __shared__ alignas(16) char smem[9216];
    const int lid = blockIdx.x, t = threadIdx.x;
    if (lid < 128)        dev_sq(R, R + 250000, Q, lid, t, smem);
    else                  dev_vec(R, R + 250000, u4, u5, lid - 128, t, smem);
}

__global__ __launch_bounds__(256, 2) void hstep(
    const float* hidden, const float* Q, float* Hsum)
{
    __shared__ alignas(16) char smem[9216];
    dev_hbt(hidden, Q, Q + 250000, Hsum, blockIdx.x, threadIdx.x, smem);
}

__global__ __launch_bounds__(256) void out_final(
    const float* __restrict__ Cp, const float* __restrict__ l2b,
    const float* __restrict__ Hsum, const float* __restrict__ u32,
    const float* __restrict__ ow, const float* __restrict__ ob,
    float* __restrict__ out, float* __restrict__ hout)
{
    const int b = blockIdx.x, t = threadIdx.x;
    __shared__ float sj[512];
    __shared__ float red[10][4];
    for (int j = t; j < 500; j += 256) {
        float ih = l2b[j];
#pragma unroll
        for (int zz = 0; zz < 8; ++zz)
            ih += Cp[(size_t)zz * 262144 + (size_t)b * 512 + j];
        float h = u32[j] + Hsum[(size_t)b * 500 + j] +
                  Hsum[256000 + (size_t)b * 500 + j];
        hout[(size_t)b * 500 + j] = h;
        sj[j] = ih + h;
    }
    __syncthreads();
    const int w = t >> 6;
    for (int o = 0; o < 10; ++o) {
        float acc = 0.f;
        if (t < 500) acc += sj[t] * ow[o * 500 + t];
        if (t + 256 < 500) acc += sj[t + 256] * ow[o * 500 + t + 256];
        for (int off = 32; off; off >>= 1) acc += __shfl_down(acc, off);
        if ((t & 63) == 0) red[o][w] = acc;
    }
    __syncthreads();
    if (t < 10)
        out[(size_t)b * 10 + t] =
            fmaxf(red[t][0] + red[t][1] + red[t][2] + red[t][3] + ob[t], 0.f);
}

extern "C" void kernel_launch(void* const* d_in, const int* in_sizes, int n_in,
                              void* d_out, int out_size, void* d_ws, size_t ws_size,
                              hipStream_t stream) {
    const float* hand   = (const float*)d_in[0];
    const float* hidden = (const float*)d_in[1];
    const float* lcw = (const float*)d_in[2];
    const float* lcb = (const float*)d_in[3];
    const float* lfw = (const float*)d_in[4];
    const float* lfb = (const float*)d_in[5];
    const float* rcw = (const float*)d_in[6];
    const float* rcb = (const float*)d_in[7];
    const float* rfw = (const float*)d_in[8];
    const float* rfb = (const float*)d_in[9];
    const float* w2  = (const float*)d_in[10];
    const float* b2  = (const float*)d_in[11];
    const float* l2w = (const float*)d_in[12];
    const float* l2b = (const float*)d_in[13];
    const float* hw  = (const float*)d_in[14];
    const float* hb  = (const float*)d_in[15];
    const float* ow  = (const float*)d_in[16];
    const float* ob  = (const float*)d_in[17];

    char* wsb = (char*)d_ws;
    // [0, 8MB): Cp (8x1MB, written in step3).  Early overlay: hp/both (dead
    // by the time Cp is written).
    float* Cp   = (float*)wsb;
    float* hpL  = (float*)wsb;                    // 622,592 B
    float* hpR  = (float*)(wsb + 622592);
    float* both = (float*)(wsb + 1245184);        // ends @ 2,473,984
    unsigned short* featb = (unsigned short*)(wsb + 8388608);   // 9,764,864 B
    unsigned short* wbf   = (unsigned short*)(wsb + 18153472);  // 9,764,864 B
    float* Q   = (float*)(wsb + 27918336);        // 2 x 250000 f
    float* R   = (float*)(wsb + 29918336);        // 2 x 250000 f
    float* u1  = (float*)(wsb + 31918336);
    float* u2  = u1 + 512;
    float* u3  = u2 + 512;
    float* u4  = u3 + 512;
    float* u5  = u4 + 512;
    float* Hsum = (float*)(wsb + 31928576);       // 2 x 256000 f

    float* out  = (float*)d_out;
    float* hout = out + 5120;

    const float* hand31 = hand + (size_t)31 * 512 * 84;

    // L0: cvt_w | hand_conv | sq lvl0 (hw -> Q) | vec lvl0 (hb -> u1)
    prep0<<<3524, 256, 0, stream>>>(l2w, wbf, hand31, lcw, lcb, rcw, rcb,
                                    hpL, hpR, hw, Q, hb, u1);
    // L1: fc | sq lvl1 (Q -> R) | vec lvl1
    step1<<<708, 256, 0, stream>>>(hpL, hpR, lfw, rfw, lfb, rfb, both,
                                   Q, R, u1, u2);
    // L2: conv2 | sq lvl2 (R -> Q) | vec lvl2
    step2<<<1140, 256, 0, stream>>>(both, w2, b2, featb, R, Q, u2, u3);
    // L3: mfma (XCD-bound) | sq lvl3 (Q -> R) | vec lvl3
    step3<<<1140, 256, 0, stream>>>(featb, wbf, Cp, Q, R, u3, u4);
    // L4: sq lvl4 (R -> Q = P32 partials) | vec lvl4 (-> u5 = u32)
    step4<<<628, 256, 0, stream>>>(R, Q, u4, u5);
    // L5: h partials = hidden @ (Q0+Q1)^T
    hstep<<<128, 256, 0, stream>>>(hidden, Q, Hsum);
    // L6: final reduce + output GEMV
    out_final<<<512, 256, 0, stream>>>(Cp, l2b, Hsum, u5, ow, ob, out, hout);
}